// Round 7
// baseline (914.221 us; speedup 1.0000x reference)
//
#include <hip/hip_runtime.h>

// ---------------------------------------------------------------------------
// GCN forward: h0=[time,type] -> GraphConv(relu) -> GraphConv(relu)
//              -> per-graph mean pool -> linear [G,2]
//
//  * degrees via int atomics; scales = 1/sqrt(max(deg,1))
//  * CSR-by-dst (histogram + 3-kernel device-wide scan + bucket fill)
//  * vpack: CSR-based layer-1 aggregate fused with pack build (no atomics);
//    gathers a single pre-packed float2 {os*t, os*u} per edge (1 line, not 3)
//  * agg: WAVE per node; per edge RECOMPUTE h1[src]=relu(v_src@W1+b1) in regs
//  * gemm_pool: h2 = relu(agg2@W2+b2); p = h2@Wc; pool[g] += p.
//    BM=128 BN=128 BK=16, 8x8/thread, dbuf LDS 32 KB -> 4 blk/CU.
//    Conflict-free LDS maps: B cols tc*4 / 64+tc*4 (16B lane stride),
//    A k-major broadcast reads, 2-way-free transpose writes.
//    Stage(t+1) issued BEFORE compute(t); LDS write after; 1 barrier/tile.
// ---------------------------------------------------------------------------

#define HDIM 256

__global__ __launch_bounds__(256) void deg_kernel(
    const int* __restrict__ src, const int* __restrict__ dst,
    int* __restrict__ deg_out, int* __restrict__ deg_in, int E)
{
    int e = blockIdx.x * 256 + threadIdx.x;
    if (e < E) {
        atomicAdd(&deg_out[src[e]], 1);
        atomicAdd(&deg_in[dst[e]], 1);
    }
}

__global__ __launch_bounds__(256) void node_kernel(
    const int* __restrict__ deg_out, const int* __restrict__ deg_in,
    const int* __restrict__ gid, const float* __restrict__ t,
    const float* __restrict__ u, float* __restrict__ os,
    float* __restrict__ isc, float2* __restrict__ pre,
    int* __restrict__ gcnt, int N)
{
    int i = blockIdx.x * 256 + threadIdx.x;
    if (i < N) {
        float o = 1.0f / sqrtf(fmaxf((float)deg_out[i], 1.0f));
        os[i]  = o;
        isc[i] = 1.0f / sqrtf(fmaxf((float)deg_in[i], 1.0f));
        pre[i] = make_float2(o * t[i], o * u[i]);
        atomicAdd(&gcnt[gid[i]], 1);
    }
}

// ---- device-wide exclusive scan of deg_in (3 kernels, N <= 64*1024) --------
__global__ __launch_bounds__(1024) void scan_local_kernel(
    const int* __restrict__ deg, int* __restrict__ loc,
    int* __restrict__ partials, int N)
{
    __shared__ int lds[1024];
    int tid = threadIdx.x;
    int idx = blockIdx.x * 1024 + tid;
    int x = (idx < N) ? deg[idx] : 0;
    int val = x;
    lds[tid] = val;
    __syncthreads();
    for (int d = 1; d < 1024; d <<= 1) {
        int tv = (tid >= d) ? lds[tid - d] : 0;
        __syncthreads();
        val += tv;
        lds[tid] = val;
        __syncthreads();
    }
    if (idx < N) loc[idx] = val - x;              // exclusive within block
    if (tid == 1023) partials[blockIdx.x] = val;  // block total
}

__global__ __launch_bounds__(64) void scan_partials_kernel(
    int* __restrict__ partials, int nb)
{
    int lane = threadIdx.x;
    int x = (lane < nb) ? partials[lane] : 0;
    int v = x;
    #pragma unroll
    for (int d = 1; d < 64; d <<= 1) {
        int tv = __shfl_up(v, d);
        if (lane >= d) v += tv;
    }
    if (lane < nb) partials[lane] = v - x;        // exclusive
}

__global__ __launch_bounds__(256) void scan_add_kernel(
    const int* __restrict__ loc, const int* __restrict__ partials,
    int* __restrict__ offs, int* __restrict__ cursor, int N, int E)
{
    int i = blockIdx.x * 256 + threadIdx.x;
    if (i < N) {
        int vv = loc[i] + partials[i >> 10];
        offs[i] = vv;
        cursor[i] = vv;
    }
    if (i == 0) offs[N] = E;
}
// ---------------------------------------------------------------------------

__global__ __launch_bounds__(256) void fill_csr_kernel(
    const int* __restrict__ src, const int* __restrict__ dst,
    int* __restrict__ cursor, int* __restrict__ csr, int E)
{
    int e = blockIdx.x * 256 + threadIdx.x;
    if (e < E) {
        int pos = atomicAdd(&cursor[dst[e]], 1);
        csr[pos] = src[e];
    }
}

// layer-1 aggregate via CSR (no atomics) fused with pack build.
// per edge: ONE float2 gather (pre = {os*t, os*u}).
__global__ __launch_bounds__(256) void vpack_kernel(
    const int* __restrict__ offs, const int* __restrict__ csr,
    const float2* __restrict__ pre, const float* __restrict__ os,
    const float* __restrict__ isc, float4* __restrict__ pack, int N)
{
    int grp = threadIdx.x >> 4;
    int l   = threadIdx.x & 15;
    int i = blockIdx.x * 16 + grp;
    if (i >= N) return;
    int e0 = offs[i], e1 = offs[i + 1];
    float a0 = 0.0f, a1 = 0.0f;
    for (int e = e0 + l; e < e1; e += 16) {
        float2 pv = pre[csr[e]];
        a0 += pv.x;
        a1 += pv.y;
    }
    #pragma unroll
    for (int d = 8; d; d >>= 1) {
        a0 += __shfl_xor(a0, d);
        a1 += __shfl_xor(a1, d);
    }
    if (l == 0) {
        float s2 = isc[i];
        pack[i] = make_float4(a0 * s2, a1 * s2, os[i], 0.0f);
    }
}

// one WAVE per node; lane owns channels lane + 64q (q=0..3).
__global__ __launch_bounds__(256) void agg_kernel(
    const int* __restrict__ offs, const int* __restrict__ csr,
    const float4* __restrict__ pack, const float* __restrict__ isc,
    const float* __restrict__ W1, const float* __restrict__ b1,
    float* __restrict__ agg2, int N)
{
    int wave = threadIdx.x >> 6;
    int lane = threadIdx.x & 63;
    int i = blockIdx.x * 4 + wave;
    if (i >= N) return;

    float w0[4], w1[4], bb[4], acc[4] = {0.f, 0.f, 0.f, 0.f};
    #pragma unroll
    for (int q = 0; q < 4; ++q) {
        int j = lane + 64 * q;
        w0[q] = W1[j];
        w1[q] = W1[HDIM + j];
        bb[q] = b1[j];
    }

    int e0 = offs[i], e1 = offs[i + 1];
    for (int e = e0; e < e1; ++e) {
        int s = csr[e];
        float4 pk = pack[s];
        #pragma unroll
        for (int q = 0; q < 4; ++q) {
            float h = fmaxf(fmaf(pk.x, w0[q], fmaf(pk.y, w1[q], bb[q])), 0.0f);
            acc[q] = fmaf(pk.z, h, acc[q]);
        }
    }
    float s2 = isc[i];
    #pragma unroll
    for (int q = 0; q < 4; ++q)
        agg2[(size_t)i * HDIM + lane + 64 * q] = acc[q] * s2;
}

// fused GEMM + pool. BM=128 BN=128 BK=16; 256 thr; 8x8 per thread.
// tr=tid>>4 (16 row-groups of 8), tc=tid&15 (cols tc*4 and 64+tc*4).
__global__ __launch_bounds__(256, 4) void gemm_pool_kernel(
    const float* __restrict__ agg2, const float* __restrict__ W2,
    const float* __restrict__ b2, const float* __restrict__ Wc,
    const int* __restrict__ gid, float* __restrict__ pool, int N)
{
    __shared__ float Ab[2][16][128];   // k-major A tiles (dbuf) 16 KB
    __shared__ float Bb[2][16][128];   // row-major B tiles (dbuf) 16 KB
    int tid  = threadIdx.x;
    int bm   = blockIdx.x >> 1;
    int bn   = blockIdx.x & 1;
    int m0   = bm * 128;
    int n0   = bn * 128;
    int tr   = tid >> 4;
    int tc   = tid & 15;
    int w    = tid >> 6;
    int lane = tid & 63;
    int r    = tid >> 1;           // A staging row 0..127
    int kq8  = (tid & 1) * 8;      // A staging k sub-offset

    float acc[8][8] = {};

    // ---- staging helpers -------------------------------------------------
    // B: 16 rows x 512B; 8 wave-issues of 1KB (2 rows); wave w does {w, w+4}.
    // A: each thread 2x float4 from agg2[row=m0+r][k0+kq8(+4)]; LDS write deferred.
    auto stage_issue = [&](int t1, int buf, float4& aA0, float4& aA1) {
        int k0 = t1 * 16;
        #pragma unroll
        for (int ii = 0; ii < 2; ++ii) {
            int issue = w + ii * 4;                  // 0..7
            int rw    = issue * 2 + (lane >> 5);     // B tile row (per-lane src)
            int col   = (lane & 31) * 4;
            const float* gsrc = W2 + (size_t)(k0 + rw) * HDIM + n0 + col;
            __builtin_amdgcn_global_load_lds(
                (const __attribute__((address_space(1))) unsigned int*)gsrc,
                (__attribute__((address_space(3))) unsigned int*)&Bb[buf][issue * 2][0],
                16, 0, 0);
        }
        int row = m0 + r;
        if (row > N - 1) row = N - 1;      // clamp: rows >= N discarded at epilogue
        const float* asrc = &agg2[(size_t)row * HDIM + k0 + kq8];
        aA0 = *(const float4*)(asrc);
        aA1 = *(const float4*)(asrc + 4);
    };
    auto stage_write = [&](int buf, const float4& aA0, const float4& aA1) {
        Ab[buf][kq8 + 0][r] = aA0.x;
        Ab[buf][kq8 + 1][r] = aA0.y;
        Ab[buf][kq8 + 2][r] = aA0.z;
        Ab[buf][kq8 + 3][r] = aA0.w;
        Ab[buf][kq8 + 4][r] = aA1.x;
        Ab[buf][kq8 + 5][r] = aA1.y;
        Ab[buf][kq8 + 6][r] = aA1.z;
        Ab[buf][kq8 + 7][r] = aA1.w;
    };

    // ---- prologue --------------------------------------------------------
    {
        float4 a0, a1;
        stage_issue(0, 0, a0, a1);
        stage_write(0, a0, a1);
    }
    __syncthreads();

    // ---- main loop: issue(t+1) -> compute(t) -> write(t+1) -> barrier ----
    for (int t = 0; t < 16; ++t) {
        int b = t & 1;
        float4 aN0, aN1;
        if (t < 15) stage_issue(t + 1, b ^ 1, aN0, aN1);

        const float* Ak = &Ab[b][0][0];
        const float* Bk = &Bb[b][0][0];
        #pragma unroll 4
        for (int kk = 0; kk < 16; ++kk) {
            float4 a0 = *(const float4*)(Ak + kk * 128 + tr * 8);      // bcast
            float4 a1 = *(const float4*)(Ak + kk * 128 + tr * 8 + 4);  // bcast
            float4 b0 = *(const float4*)(Bk + kk * 128 + tc * 4);      // 16B stride
            float4 b1 = *(const float4*)(Bk + kk * 128 + 64 + tc * 4);
            float av[8] = {a0.x, a0.y, a0.z, a0.w, a1.x, a1.y, a1.z, a1.w};
            float bv[8] = {b0.x, b0.y, b0.z, b0.w, b1.x, b1.y, b1.z, b1.w};
            #pragma unroll
            for (int i = 0; i < 8; ++i)
                #pragma unroll
                for (int j = 0; j < 8; ++j)
                    acc[i][j] = fmaf(av[i], bv[j], acc[i][j]);
        }

        if (t < 15) stage_write(b ^ 1, aN0, aN1);
        __syncthreads();
    }

    // ---- epilogue: bias+relu, project to 2, 16-lane reduce, atomic pool --
    float pc[8][2] = {};
    #pragma unroll
    for (int j = 0; j < 8; ++j) {
        int col = n0 + ((j < 4) ? (tc * 4 + j) : (64 + tc * 4 + (j - 4)));
        float bcol = b2[col];
        float wc0 = Wc[col * 2 + 0], wc1 = Wc[col * 2 + 1];
        #pragma unroll
        for (int i = 0; i < 8; ++i) {
            float h = fmaxf(acc[i][j] + bcol, 0.0f);
            pc[i][0] = fmaf(h, wc0, pc[i][0]);
            pc[i][1] = fmaf(h, wc1, pc[i][1]);
        }
    }
    #pragma unroll
    for (int off = 8; off > 0; off >>= 1) {
        #pragma unroll
        for (int i = 0; i < 8; ++i) {
            pc[i][0] += __shfl_xor(pc[i][0], off);
            pc[i][1] += __shfl_xor(pc[i][1], off);
        }
    }
    if (tc == 0) {
        #pragma unroll
        for (int i = 0; i < 8; ++i) {
            int rr = m0 + tr * 8 + i;
            if (rr < N) {
                int g = gid[rr];
                atomicAdd(&pool[g * 2 + 0], pc[i][0]);
                atomicAdd(&pool[g * 2 + 1], pc[i][1]);
            }
        }
    }
}

__global__ __launch_bounds__(256) void finalize_kernel(
    const float* __restrict__ pool, const int* __restrict__ gcnt,
    const float* __restrict__ bc, float* __restrict__ out, int G)
{
    int g = threadIdx.x;
    if (g < G) {
        float c = fmaxf((float)gcnt[g], 1.0f);
        out[2 * g + 0] = pool[2 * g + 0] / c + bc[0];
        out[2 * g + 1] = pool[2 * g + 1] / c + bc[1];
    }
}

extern "C" void kernel_launch(void* const* d_in, const int* in_sizes, int n_in,
                              void* d_out, int out_size, void* d_ws, size_t ws_size,
                              hipStream_t stream)
{
    const float* t  = (const float*)d_in[0];
    const float* u  = (const float*)d_in[1];
    const int* esrc = (const int*)d_in[2];
    const int* edst = (const int*)d_in[3];
    const int* gid  = (const int*)d_in[4];
    const float* W1 = (const float*)d_in[6];
    const float* b1 = (const float*)d_in[7];
    const float* W2 = (const float*)d_in[8];
    const float* b2 = (const float*)d_in[9];
    const float* Wc = (const float*)d_in[10];
    const float* bc = (const float*)d_in[11];
    float* out = (float*)d_out;

    int N = in_sizes[0];
    int E = in_sizes[2];
    int G = out_size / 2;

    char* ws = (char*)d_ws;
    size_t off = 0;
    auto take = [&](size_t bytes) {
        size_t o = off;
        off += (bytes + 15) & ~(size_t)15;
        return o;
    };
    int*    deg_out = (int*)   (ws + take(4 * (size_t)N));
    int*    deg_in  = (int*)   (ws + take(4 * (size_t)N));
    float*  pool    = (float*) (ws + take(8 * (size_t)G));
    int*    gcnt    = (int*)   (ws + take(4 * (size_t)G));
    size_t  zbytes  = off;                               // zero everything above
    float*  os      = (float*) (ws + take(4 * (size_t)N));
    float*  isc     = (float*) (ws + take(4 * (size_t)N));
    float2* pre     = (float2*)(ws + take(8 * (size_t)N));
    int*    offs    = (int*)   (ws + take(4 * (size_t)(N + 1)));
    int*    cursor  = (int*)   (ws + take(4 * (size_t)N));
    int*    loc     = (int*)   (ws + take(4 * (size_t)N));
    int*    partials= (int*)   (ws + take(4 * 64));
    int*    csr     = (int*)   (ws + take(4 * (size_t)E));
    float4* pack    = (float4*)(ws + take(16 * (size_t)N));
    float*  agg2    = (float*) (ws + take((size_t)N * HDIM * 4));

    hipMemsetAsync(ws, 0, zbytes, stream);

    int eb = (E + 255) / 256;
    int nb = (N + 255) / 256;
    int sb = (N + 1023) / 1024;     // scan blocks (<=64 for N<=65536)
    deg_kernel          <<<eb, 256, 0, stream>>>(esrc, edst, deg_out, deg_in, E);
    node_kernel         <<<nb, 256, 0, stream>>>(deg_out, deg_in, gid, t, u, os, isc, pre, gcnt, N);
    scan_local_kernel   <<<sb, 1024, 0, stream>>>(deg_in, loc, partials, N);
    scan_partials_kernel<<<1, 64, 0, stream>>>(partials, sb);
    scan_add_kernel     <<<nb, 256, 0, stream>>>(loc, partials, offs, cursor, N, E);
    fill_csr_kernel     <<<eb, 256, 0, stream>>>(esrc, edst, cursor, csr, E);
    vpack_kernel        <<<(N + 15) / 16, 256, 0, stream>>>(offs, csr, pre, os, isc, pack, N);
    agg_kernel          <<<(N + 3) / 4, 256, 0, stream>>>(offs, csr, pack, isc, W1, b1, agg2, N);
    gemm_pool_kernel    <<<((N + 127) / 128) * 2, 256, 0, stream>>>(agg2, W2, b2, Wc, gid, pool, N);
    finalize_kernel     <<<1, 256, 0, stream>>>(pool, gcnt, bc, out, G);
}

// Round 8
// 838.559 us; speedup vs baseline: 1.0902x; 1.0902x over previous
//
#include <hip/hip_runtime.h>

// ---------------------------------------------------------------------------
// GCN forward: h0=[time,type] -> GraphConv(relu) -> GraphConv(relu)
//              -> per-graph mean pool -> linear [G,2]
//
//  * degrees via int atomics; scales = 1/sqrt(max(deg,1))
//  * CSR-by-dst (histogram + 3-kernel device-wide scan + bucket fill)
//  * vpack: CSR-based layer-1 aggregate fused with pack build (no atomics);
//    gathers a single pre-packed float2 {os*t, os*u} per edge (1 line, not 3)
//  * agg: WAVE per node; per edge RECOMPUTE h1[src]=relu(v_src@W1+b1) in regs
//  * gemm_pool: h2 = relu(agg2@W2+b2); p = h2@Wc; pool[g] += p.
//    BM=128 BN=128 BK=16, 8x8/thread, dbuf LDS 32 KB.
//    NO launch_bounds min-waves: round-7 showed (256,4) caps regs at 128 and
//    spills acc -> 124 MB scratch writes. Spill-free at 3 blk/CU is faster.
//    Conflict-free LDS maps: B cols tc*4 / 64+tc*4, A k-major bcast reads.
//    Stage(t+1) issued BEFORE compute(t); LDS write after; 1 barrier/tile.
// ---------------------------------------------------------------------------

#define HDIM 256

__global__ __launch_bounds__(256) void deg_kernel(
    const int* __restrict__ src, const int* __restrict__ dst,
    int* __restrict__ deg_out, int* __restrict__ deg_in, int E)
{
    int e = blockIdx.x * 256 + threadIdx.x;
    if (e < E) {
        atomicAdd(&deg_out[src[e]], 1);
        atomicAdd(&deg_in[dst[e]], 1);
    }
}

__global__ __launch_bounds__(256) void node_kernel(
    const int* __restrict__ deg_out, const int* __restrict__ deg_in,
    const int* __restrict__ gid, const float* __restrict__ t,
    const float* __restrict__ u, float* __restrict__ os,
    float* __restrict__ isc, float2* __restrict__ pre,
    int* __restrict__ gcnt, int N)
{
    int i = blockIdx.x * 256 + threadIdx.x;
    if (i < N) {
        float o = 1.0f / sqrtf(fmaxf((float)deg_out[i], 1.0f));
        os[i]  = o;
        isc[i] = 1.0f / sqrtf(fmaxf((float)deg_in[i], 1.0f));
        pre[i] = make_float2(o * t[i], o * u[i]);
        atomicAdd(&gcnt[gid[i]], 1);
    }
}

// ---- device-wide exclusive scan of deg_in (3 kernels, N <= 64*1024) --------
__global__ __launch_bounds__(1024) void scan_local_kernel(
    const int* __restrict__ deg, int* __restrict__ loc,
    int* __restrict__ partials, int N)
{
    __shared__ int lds[1024];
    int tid = threadIdx.x;
    int idx = blockIdx.x * 1024 + tid;
    int x = (idx < N) ? deg[idx] : 0;
    int val = x;
    lds[tid] = val;
    __syncthreads();
    for (int d = 1; d < 1024; d <<= 1) {
        int tv = (tid >= d) ? lds[tid - d] : 0;
        __syncthreads();
        val += tv;
        lds[tid] = val;
        __syncthreads();
    }
    if (idx < N) loc[idx] = val - x;              // exclusive within block
    if (tid == 1023) partials[blockIdx.x] = val;  // block total
}

__global__ __launch_bounds__(64) void scan_partials_kernel(
    int* __restrict__ partials, int nb)
{
    int lane = threadIdx.x;
    int x = (lane < nb) ? partials[lane] : 0;
    int v = x;
    #pragma unroll
    for (int d = 1; d < 64; d <<= 1) {
        int tv = __shfl_up(v, d);
        if (lane >= d) v += tv;
    }
    if (lane < nb) partials[lane] = v - x;        // exclusive
}

__global__ __launch_bounds__(256) void scan_add_kernel(
    const int* __restrict__ loc, const int* __restrict__ partials,
    int* __restrict__ offs, int* __restrict__ cursor, int N, int E)
{
    int i = blockIdx.x * 256 + threadIdx.x;
    if (i < N) {
        int vv = loc[i] + partials[i >> 10];
        offs[i] = vv;
        cursor[i] = vv;
    }
    if (i == 0) offs[N] = E;
}
// ---------------------------------------------------------------------------

__global__ __launch_bounds__(256) void fill_csr_kernel(
    const int* __restrict__ src, const int* __restrict__ dst,
    int* __restrict__ cursor, int* __restrict__ csr, int E)
{
    int e = blockIdx.x * 256 + threadIdx.x;
    if (e < E) {
        int pos = atomicAdd(&cursor[dst[e]], 1);
        csr[pos] = src[e];
    }
}

// layer-1 aggregate via CSR (no atomics) fused with pack build.
// per edge: ONE float2 gather (pre = {os*t, os*u}).
__global__ __launch_bounds__(256) void vpack_kernel(
    const int* __restrict__ offs, const int* __restrict__ csr,
    const float2* __restrict__ pre, const float* __restrict__ os,
    const float* __restrict__ isc, float4* __restrict__ pack, int N)
{
    int grp = threadIdx.x >> 4;
    int l   = threadIdx.x & 15;
    int i = blockIdx.x * 16 + grp;
    if (i >= N) return;
    int e0 = offs[i], e1 = offs[i + 1];
    float a0 = 0.0f, a1 = 0.0f;
    for (int e = e0 + l; e < e1; e += 16) {
        float2 pv = pre[csr[e]];
        a0 += pv.x;
        a1 += pv.y;
    }
    #pragma unroll
    for (int d = 8; d; d >>= 1) {
        a0 += __shfl_xor(a0, d);
        a1 += __shfl_xor(a1, d);
    }
    if (l == 0) {
        float s2 = isc[i];
        pack[i] = make_float4(a0 * s2, a1 * s2, os[i], 0.0f);
    }
}

// one WAVE per node; lane owns channels lane + 64q (q=0..3).
__global__ __launch_bounds__(256) void agg_kernel(
    const int* __restrict__ offs, const int* __restrict__ csr,
    const float4* __restrict__ pack, const float* __restrict__ isc,
    const float* __restrict__ W1, const float* __restrict__ b1,
    float* __restrict__ agg2, int N)
{
    int wave = threadIdx.x >> 6;
    int lane = threadIdx.x & 63;
    int i = blockIdx.x * 4 + wave;
    if (i >= N) return;

    float w0[4], w1[4], bb[4], acc[4] = {0.f, 0.f, 0.f, 0.f};
    #pragma unroll
    for (int q = 0; q < 4; ++q) {
        int j = lane + 64 * q;
        w0[q] = W1[j];
        w1[q] = W1[HDIM + j];
        bb[q] = b1[j];
    }

    int e0 = offs[i], e1 = offs[i + 1];
    for (int e = e0; e < e1; ++e) {
        int s = csr[e];
        float4 pk = pack[s];
        #pragma unroll
        for (int q = 0; q < 4; ++q) {
            float h = fmaxf(fmaf(pk.x, w0[q], fmaf(pk.y, w1[q], bb[q])), 0.0f);
            acc[q] = fmaf(pk.z, h, acc[q]);
        }
    }
    float s2 = isc[i];
    #pragma unroll
    for (int q = 0; q < 4; ++q)
        agg2[(size_t)i * HDIM + lane + 64 * q] = acc[q] * s2;
}

// fused GEMM + pool. BM=128 BN=128 BK=16; 256 thr; 8x8 per thread.
// tr=tid>>4 (16 row-groups of 8), tc=tid&15 (cols tc*4 and 64+tc*4).
__global__ __launch_bounds__(256) void gemm_pool_kernel(
    const float* __restrict__ agg2, const float* __restrict__ W2,
    const float* __restrict__ b2, const float* __restrict__ Wc,
    const int* __restrict__ gid, float* __restrict__ pool, int N)
{
    __shared__ float Ab[2][16][128];   // k-major A tiles (dbuf) 16 KB
    __shared__ float Bb[2][16][128];   // row-major B tiles (dbuf) 16 KB
    int tid  = threadIdx.x;
    int bm   = blockIdx.x >> 1;
    int bn   = blockIdx.x & 1;
    int m0   = bm * 128;
    int n0   = bn * 128;
    int tr   = tid >> 4;
    int tc   = tid & 15;
    int w    = tid >> 6;
    int lane = tid & 63;
    int r    = tid >> 1;           // A staging row 0..127
    int kq8  = (tid & 1) * 8;      // A staging k sub-offset

    float acc[8][8] = {};

    // ---- staging helpers -------------------------------------------------
    // B: 16 rows x 512B; 8 wave-issues of 1KB (2 rows); wave w does {w, w+4}.
    // A: each thread 2x float4 from agg2[row=m0+r][k0+kq8(+4)]; LDS write deferred.
    auto stage_issue = [&](int t1, int buf, float4& aA0, float4& aA1) {
        int k0 = t1 * 16;
        #pragma unroll
        for (int ii = 0; ii < 2; ++ii) {
            int issue = w + ii * 4;                  // 0..7
            int rw    = issue * 2 + (lane >> 5);     // B tile row (per-lane src)
            int col   = (lane & 31) * 4;
            const float* gsrc = W2 + (size_t)(k0 + rw) * HDIM + n0 + col;
            __builtin_amdgcn_global_load_lds(
                (const __attribute__((address_space(1))) unsigned int*)gsrc,
                (__attribute__((address_space(3))) unsigned int*)&Bb[buf][issue * 2][0],
                16, 0, 0);
        }
        int row = m0 + r;
        if (row > N - 1) row = N - 1;      // clamp: rows >= N discarded at epilogue
        const float* asrc = &agg2[(size_t)row * HDIM + k0 + kq8];
        aA0 = *(const float4*)(asrc);
        aA1 = *(const float4*)(asrc + 4);
    };
    auto stage_write = [&](int buf, const float4& aA0, const float4& aA1) {
        Ab[buf][kq8 + 0][r] = aA0.x;
        Ab[buf][kq8 + 1][r] = aA0.y;
        Ab[buf][kq8 + 2][r] = aA0.z;
        Ab[buf][kq8 + 3][r] = aA0.w;
        Ab[buf][kq8 + 4][r] = aA1.x;
        Ab[buf][kq8 + 5][r] = aA1.y;
        Ab[buf][kq8 + 6][r] = aA1.z;
        Ab[buf][kq8 + 7][r] = aA1.w;
    };

    // ---- prologue --------------------------------------------------------
    {
        float4 a0, a1;
        stage_issue(0, 0, a0, a1);
        stage_write(0, a0, a1);
    }
    __syncthreads();

    // ---- main loop: issue(t+1) -> compute(t) -> write(t+1) -> barrier ----
    for (int t = 0; t < 16; ++t) {
        int b = t & 1;
        float4 aN0, aN1;
        if (t < 15) stage_issue(t + 1, b ^ 1, aN0, aN1);

        const float* Ak = &Ab[b][0][0];
        const float* Bk = &Bb[b][0][0];
        #pragma unroll 4
        for (int kk = 0; kk < 16; ++kk) {
            float4 a0 = *(const float4*)(Ak + kk * 128 + tr * 8);      // bcast
            float4 a1 = *(const float4*)(Ak + kk * 128 + tr * 8 + 4);  // bcast
            float4 b0 = *(const float4*)(Bk + kk * 128 + tc * 4);      // 16B stride
            float4 b1 = *(const float4*)(Bk + kk * 128 + 64 + tc * 4);
            acc[0][0] = fmaf(a0.x, b0.x, acc[0][0]); acc[0][1] = fmaf(a0.x, b0.y, acc[0][1]);
            acc[0][2] = fmaf(a0.x, b0.z, acc[0][2]); acc[0][3] = fmaf(a0.x, b0.w, acc[0][3]);
            acc[0][4] = fmaf(a0.x, b1.x, acc[0][4]); acc[0][5] = fmaf(a0.x, b1.y, acc[0][5]);
            acc[0][6] = fmaf(a0.x, b1.z, acc[0][6]); acc[0][7] = fmaf(a0.x, b1.w, acc[0][7]);
            acc[1][0] = fmaf(a0.y, b0.x, acc[1][0]); acc[1][1] = fmaf(a0.y, b0.y, acc[1][1]);
            acc[1][2] = fmaf(a0.y, b0.z, acc[1][2]); acc[1][3] = fmaf(a0.y, b0.w, acc[1][3]);
            acc[1][4] = fmaf(a0.y, b1.x, acc[1][4]); acc[1][5] = fmaf(a0.y, b1.y, acc[1][5]);
            acc[1][6] = fmaf(a0.y, b1.z, acc[1][6]); acc[1][7] = fmaf(a0.y, b1.w, acc[1][7]);
            acc[2][0] = fmaf(a0.z, b0.x, acc[2][0]); acc[2][1] = fmaf(a0.z, b0.y, acc[2][1]);
            acc[2][2] = fmaf(a0.z, b0.z, acc[2][2]); acc[2][3] = fmaf(a0.z, b0.w, acc[2][3]);
            acc[2][4] = fmaf(a0.z, b1.x, acc[2][4]); acc[2][5] = fmaf(a0.z, b1.y, acc[2][5]);
            acc[2][6] = fmaf(a0.z, b1.z, acc[2][6]); acc[2][7] = fmaf(a0.z, b1.w, acc[2][7]);
            acc[3][0] = fmaf(a0.w, b0.x, acc[3][0]); acc[3][1] = fmaf(a0.w, b0.y, acc[3][1]);
            acc[3][2] = fmaf(a0.w, b0.z, acc[3][2]); acc[3][3] = fmaf(a0.w, b0.w, acc[3][3]);
            acc[3][4] = fmaf(a0.w, b1.x, acc[3][4]); acc[3][5] = fmaf(a0.w, b1.y, acc[3][5]);
            acc[3][6] = fmaf(a0.w, b1.z, acc[3][6]); acc[3][7] = fmaf(a0.w, b1.w, acc[3][7]);
            acc[4][0] = fmaf(a1.x, b0.x, acc[4][0]); acc[4][1] = fmaf(a1.x, b0.y, acc[4][1]);
            acc[4][2] = fmaf(a1.x, b0.z, acc[4][2]); acc[4][3] = fmaf(a1.x, b0.w, acc[4][3]);
            acc[4][4] = fmaf(a1.x, b1.x, acc[4][4]); acc[4][5] = fmaf(a1.x, b1.y, acc[4][5]);
            acc[4][6] = fmaf(a1.x, b1.z, acc[4][6]); acc[4][7] = fmaf(a1.x, b1.w, acc[4][7]);
            acc[5][0] = fmaf(a1.y, b0.x, acc[5][0]); acc[5][1] = fmaf(a1.y, b0.y, acc[5][1]);
            acc[5][2] = fmaf(a1.y, b0.z, acc[5][2]); acc[5][3] = fmaf(a1.y, b0.w, acc[5][3]);
            acc[5][4] = fmaf(a1.y, b1.x, acc[5][4]); acc[5][5] = fmaf(a1.y, b1.y, acc[5][5]);
            acc[5][6] = fmaf(a1.y, b1.z, acc[5][6]); acc[5][7] = fmaf(a1.y, b1.w, acc[5][7]);
            acc[6][0] = fmaf(a1.z, b0.x, acc[6][0]); acc[6][1] = fmaf(a1.z, b0.y, acc[6][1]);
            acc[6][2] = fmaf(a1.z, b0.z, acc[6][2]); acc[6][3] = fmaf(a1.z, b0.w, acc[6][3]);
            acc[6][4] = fmaf(a1.z, b1.x, acc[6][4]); acc[6][5] = fmaf(a1.z, b1.y, acc[6][5]);
            acc[6][6] = fmaf(a1.z, b1.z, acc[6][6]); acc[6][7] = fmaf(a1.z, b1.w, acc[6][7]);
            acc[7][0] = fmaf(a1.w, b0.x, acc[7][0]); acc[7][1] = fmaf(a1.w, b0.y, acc[7][1]);
            acc[7][2] = fmaf(a1.w, b0.z, acc[7][2]); acc[7][3] = fmaf(a1.w, b0.w, acc[7][3]);
            acc[7][4] = fmaf(a1.w, b1.x, acc[7][4]); acc[7][5] = fmaf(a1.w, b1.y, acc[7][5]);
            acc[7][6] = fmaf(a1.w, b1.z, acc[7][6]); acc[7][7] = fmaf(a1.w, b1.w, acc[7][7]);
        }

        if (t < 15) stage_write(b ^ 1, aN0, aN1);
        __syncthreads();
    }

    // ---- epilogue: bias+relu, project to 2, 16-lane reduce, atomic pool --
    float pc[8][2] = {};
    #pragma unroll
    for (int j = 0; j < 8; ++j) {
        int col = n0 + ((j < 4) ? (tc * 4 + j) : (64 + tc * 4 + (j - 4)));
        float bcol = b2[col];
        float wc0 = Wc[col * 2 + 0], wc1 = Wc[col * 2 + 1];
        #pragma unroll
        for (int i = 0; i < 8; ++i) {
            float h = fmaxf(acc[i][j] + bcol, 0.0f);
            pc[i][0] = fmaf(h, wc0, pc[i][0]);
            pc[i][1] = fmaf(h, wc1, pc[i][1]);
        }
    }
    #pragma unroll
    for (int off = 8; off > 0; off >>= 1) {
        #pragma unroll
        for (int i = 0; i < 8; ++i) {
            pc[i][0] += __shfl_xor(pc[i][0], off);
            pc[i][1] += __shfl_xor(pc[i][1], off);
        }
    }
    if (tc == 0) {
        #pragma unroll
        for (int i = 0; i < 8; ++i) {
            int rr = m0 + tr * 8 + i;
            if (rr < N) {
                int g = gid[rr];
                atomicAdd(&pool[g * 2 + 0], pc[i][0]);
                atomicAdd(&pool[g * 2 + 1], pc[i][1]);
            }
        }
    }
}

__global__ __launch_bounds__(256) void finalize_kernel(
    const float* __restrict__ pool, const int* __restrict__ gcnt,
    const float* __restrict__ bc, float* __restrict__ out, int G)
{
    int g = threadIdx.x;
    if (g < G) {
        float c = fmaxf((float)gcnt[g], 1.0f);
        out[2 * g + 0] = pool[2 * g + 0] / c + bc[0];
        out[2 * g + 1] = pool[2 * g + 1] / c + bc[1];
    }
}

extern "C" void kernel_launch(void* const* d_in, const int* in_sizes, int n_in,
                              void* d_out, int out_size, void* d_ws, size_t ws_size,
                              hipStream_t stream)
{
    const float* t  = (const float*)d_in[0];
    const float* u  = (const float*)d_in[1];
    const int* esrc = (const int*)d_in[2];
    const int* edst = (const int*)d_in[3];
    const int* gid  = (const int*)d_in[4];
    const float* W1 = (const float*)d_in[6];
    const float* b1 = (const float*)d_in[7];
    const float* W2 = (const float*)d_in[8];
    const float* b2 = (const float*)d_in[9];
    const float* Wc = (const float*)d_in[10];
    const float* bc = (const float*)d_in[11];
    float* out = (float*)d_out;

    int N = in_sizes[0];
    int E = in_sizes[2];
    int G = out_size / 2;

    char* ws = (char*)d_ws;
    size_t off = 0;
    auto take = [&](size_t bytes) {
        size_t o = off;
        off += (bytes + 15) & ~(size_t)15;
        return o;
    };
    int*    deg_out = (int*)   (ws + take(4 * (size_t)N));
    int*    deg_in  = (int*)   (ws + take(4 * (size_t)N));
    float*  pool    = (float*) (ws + take(8 * (size_t)G));
    int*    gcnt    = (int*)   (ws + take(4 * (size_t)G));
    size_t  zbytes  = off;                               // zero everything above
    float*  os      = (float*) (ws + take(4 * (size_t)N));
    float*  isc     = (float*) (ws + take(4 * (size_t)N));
    float2* pre     = (float2*)(ws + take(8 * (size_t)N));
    int*    offs    = (int*)   (ws + take(4 * (size_t)(N + 1)));
    int*    cursor  = (int*)   (ws + take(4 * (size_t)N));
    int*    loc     = (int*)   (ws + take(4 * (size_t)N));
    int*    partials= (int*)   (ws + take(4 * 64));
    int*    csr     = (int*)   (ws + take(4 * (size_t)E));
    float4* pack    = (float4*)(ws + take(16 * (size_t)N));
    float*  agg2    = (float*) (ws + take((size_t)N * HDIM * 4));

    hipMemsetAsync(ws, 0, zbytes, stream);

    int eb = (E + 255) / 256;
    int nb = (N + 255) / 256;
    int sb = (N + 1023) / 1024;     // scan blocks (<=64 for N<=65536)
    deg_kernel          <<<eb, 256, 0, stream>>>(esrc, edst, deg_out, deg_in, E);
    node_kernel         <<<nb, 256, 0, stream>>>(deg_out, deg_in, gid, t, u, os, isc, pre, gcnt, N);
    scan_local_kernel   <<<sb, 1024, 0, stream>>>(deg_in, loc, partials, N);
    scan_partials_kernel<<<1, 64, 0, stream>>>(partials, sb);
    scan_add_kernel     <<<nb, 256, 0, stream>>>(loc, partials, offs, cursor, N, E);
    fill_csr_kernel     <<<eb, 256, 0, stream>>>(esrc, edst, cursor, csr, E);
    vpack_kernel        <<<(N + 15) / 16, 256, 0, stream>>>(offs, csr, pre, os, isc, pack, N);
    agg_kernel          <<<(N + 3) / 4, 256, 0, stream>>>(offs, csr, pack, isc, W1, b1, agg2, N);
    gemm_pool_kernel    <<<((N + 127) / 128) * 2, 256, 0, stream>>>(agg2, W2, b2, Wc, gid, pool, N);
    finalize_kernel     <<<1, 256, 0, stream>>>(pool, gcnt, bc, out, G);
}

// Round 9
// 478.860 us; speedup vs baseline: 1.9092x; 1.7512x over previous
//
#include <hip/hip_runtime.h>

// ---------------------------------------------------------------------------
// GCN forward: h0=[time,type] -> GraphConv(relu) -> GraphConv(relu)
//              -> per-graph mean pool -> linear [G,2]
//
//  * degrees via int atomics; scales = 1/sqrt(max(deg,1))
//  * CSR-by-dst (histogram + 3-kernel device-wide scan + bucket fill)
//  * vpack: CSR layer-1 aggregate fused with pack build (no atomics)
//  * agg: WAVE per node; per edge RECOMPUTE h1[src]=relu(v_src@W1+b1) in regs
//  * gemm_pool: h2 = relu(agg2@W2+b2); p = h2@Wc; pool via LDS then global.
//    ROUND 9 RETILE FOR TLP: rounds 3-8 were ~90% latency-stalled (VALU-issue
//    always ~49us = FMA floor; wall 250-530us). 8x8 tile => >=128 regs =>
//    2 waves/SIMD, loads sunk to use-site, serial mem phases. Now 8x4/thread
//    (acc=32, ~70 regs => 6+ waves/SIMD), BM=128 BN=64, grid 1564 (~6 blk/CU),
//    single-buf LDS 13.6KB. TLP hides staging latency.
// ---------------------------------------------------------------------------

#define HDIM 256

__global__ __launch_bounds__(256) void deg_kernel(
    const int* __restrict__ src, const int* __restrict__ dst,
    int* __restrict__ deg_out, int* __restrict__ deg_in, int E)
{
    int e = blockIdx.x * 256 + threadIdx.x;
    if (e < E) {
        atomicAdd(&deg_out[src[e]], 1);
        atomicAdd(&deg_in[dst[e]], 1);
    }
}

__global__ __launch_bounds__(256) void node_kernel(
    const int* __restrict__ deg_out, const int* __restrict__ deg_in,
    const int* __restrict__ gid, const float* __restrict__ t,
    const float* __restrict__ u, float* __restrict__ os,
    float* __restrict__ isc, float2* __restrict__ pre,
    int* __restrict__ gcnt, int N)
{
    int i = blockIdx.x * 256 + threadIdx.x;
    if (i < N) {
        float o = 1.0f / sqrtf(fmaxf((float)deg_out[i], 1.0f));
        os[i]  = o;
        isc[i] = 1.0f / sqrtf(fmaxf((float)deg_in[i], 1.0f));
        pre[i] = make_float2(o * t[i], o * u[i]);
        atomicAdd(&gcnt[gid[i]], 1);
    }
}

// ---- device-wide exclusive scan of deg_in (3 kernels, N <= 64*1024) --------
__global__ __launch_bounds__(1024) void scan_local_kernel(
    const int* __restrict__ deg, int* __restrict__ loc,
    int* __restrict__ partials, int N)
{
    __shared__ int lds[1024];
    int tid = threadIdx.x;
    int idx = blockIdx.x * 1024 + tid;
    int x = (idx < N) ? deg[idx] : 0;
    int val = x;
    lds[tid] = val;
    __syncthreads();
    for (int d = 1; d < 1024; d <<= 1) {
        int tv = (tid >= d) ? lds[tid - d] : 0;
        __syncthreads();
        val += tv;
        lds[tid] = val;
        __syncthreads();
    }
    if (idx < N) loc[idx] = val - x;              // exclusive within block
    if (tid == 1023) partials[blockIdx.x] = val;  // block total
}

__global__ __launch_bounds__(64) void scan_partials_kernel(
    int* __restrict__ partials, int nb)
{
    int lane = threadIdx.x;
    int x = (lane < nb) ? partials[lane] : 0;
    int v = x;
    #pragma unroll
    for (int d = 1; d < 64; d <<= 1) {
        int tv = __shfl_up(v, d);
        if (lane >= d) v += tv;
    }
    if (lane < nb) partials[lane] = v - x;        // exclusive
}

__global__ __launch_bounds__(256) void scan_add_kernel(
    const int* __restrict__ loc, const int* __restrict__ partials,
    int* __restrict__ offs, int* __restrict__ cursor, int N, int E)
{
    int i = blockIdx.x * 256 + threadIdx.x;
    if (i < N) {
        int vv = loc[i] + partials[i >> 10];
        offs[i] = vv;
        cursor[i] = vv;
    }
    if (i == 0) offs[N] = E;
}
// ---------------------------------------------------------------------------

__global__ __launch_bounds__(256) void fill_csr_kernel(
    const int* __restrict__ src, const int* __restrict__ dst,
    int* __restrict__ cursor, int* __restrict__ csr, int E)
{
    int e = blockIdx.x * 256 + threadIdx.x;
    if (e < E) {
        int pos = atomicAdd(&cursor[dst[e]], 1);
        csr[pos] = src[e];
    }
}

// layer-1 aggregate via CSR (no atomics) fused with pack build.
__global__ __launch_bounds__(256) void vpack_kernel(
    const int* __restrict__ offs, const int* __restrict__ csr,
    const float2* __restrict__ pre, const float* __restrict__ os,
    const float* __restrict__ isc, float4* __restrict__ pack, int N)
{
    int grp = threadIdx.x >> 4;
    int l   = threadIdx.x & 15;
    int i = blockIdx.x * 16 + grp;
    if (i >= N) return;
    int e0 = offs[i], e1 = offs[i + 1];
    float a0 = 0.0f, a1 = 0.0f;
    for (int e = e0 + l; e < e1; e += 16) {
        float2 pv = pre[csr[e]];
        a0 += pv.x;
        a1 += pv.y;
    }
    #pragma unroll
    for (int d = 8; d; d >>= 1) {
        a0 += __shfl_xor(a0, d);
        a1 += __shfl_xor(a1, d);
    }
    if (l == 0) {
        float s2 = isc[i];
        pack[i] = make_float4(a0 * s2, a1 * s2, os[i], 0.0f);
    }
}

// one WAVE per node; lane owns channels lane + 64q (q=0..3).
__global__ __launch_bounds__(256) void agg_kernel(
    const int* __restrict__ offs, const int* __restrict__ csr,
    const float4* __restrict__ pack, const float* __restrict__ isc,
    const float* __restrict__ W1, const float* __restrict__ b1,
    float* __restrict__ agg2, int N)
{
    int wave = threadIdx.x >> 6;
    int lane = threadIdx.x & 63;
    int i = blockIdx.x * 4 + wave;
    if (i >= N) return;

    float w0[4], w1[4], bb[4], acc[4] = {0.f, 0.f, 0.f, 0.f};
    #pragma unroll
    for (int q = 0; q < 4; ++q) {
        int j = lane + 64 * q;
        w0[q] = W1[j];
        w1[q] = W1[HDIM + j];
        bb[q] = b1[j];
    }

    int e0 = offs[i], e1 = offs[i + 1];
    for (int e = e0; e < e1; ++e) {
        int s = csr[e];
        float4 pk = pack[s];
        #pragma unroll
        for (int q = 0; q < 4; ++q) {
            float h = fmaxf(fmaf(pk.x, w0[q], fmaf(pk.y, w1[q], bb[q])), 0.0f);
            acc[q] = fmaf(pk.z, h, acc[q]);
        }
    }
    float s2 = isc[i];
    #pragma unroll
    for (int q = 0; q < 4; ++q)
        agg2[(size_t)i * HDIM + lane + 64 * q] = acc[q] * s2;
}

// fused GEMM + pool. BM=128 BN=64 BK=16; 256 thr; 8 rows x 4 cols per thread.
// tr=tid>>4 (16 row-groups of 8), tc=tid&15 (cols tc*4..+3).
// A k-major LDS [16][132] (pad: 16B-aligned rows, 2-way-free banks),
// B row-major [16][64] staged by global_load_lds (linear dest).
__global__ __launch_bounds__(256) void gemm_pool_kernel(
    const float* __restrict__ agg2, const float* __restrict__ W2,
    const float* __restrict__ b2, const float* __restrict__ Wc,
    const int* __restrict__ gid, float* __restrict__ pool, int N, int G)
{
    __shared__ float As[16][132];   // 8448 B
    __shared__ float Bs[16][64];    // 4096 B
    __shared__ float Lpool[256];    // per-block graph pool (G<=128)
    int tid  = threadIdx.x;
    int bm   = blockIdx.x >> 2;
    int bn   = blockIdx.x & 3;
    int m0   = bm * 128;
    int n0   = bn * 64;
    int tr   = tid >> 4;
    int tc   = tid & 15;
    int w    = tid >> 6;
    int lane = tid & 63;
    int r    = tid >> 1;            // A staging row 0..127
    int kq8  = (tid & 1) * 8;       // A staging k sub-offset (0 or 8)

    Lpool[tid] = 0.0f;

    float acc[8][4] = {};

    int arow = m0 + r;
    if (arow > N - 1) arow = N - 1;           // clamped rows discarded at epilogue
    const float* abase = agg2 + (size_t)arow * HDIM + kq8;
    // B source row/col for this lane (wave w stages rows w*4..w*4+3)
    const float* bsrc0 = W2 + (size_t)(w * 4 + (lane >> 4)) * HDIM + n0 + (lane & 15) * 4;

    auto write_a = [&](const float4& a0, const float4& a1) {
        As[kq8 + 0][r] = a0.x;  As[kq8 + 1][r] = a0.y;
        As[kq8 + 2][r] = a0.z;  As[kq8 + 3][r] = a0.w;
        As[kq8 + 4][r] = a1.x;  As[kq8 + 5][r] = a1.y;
        As[kq8 + 6][r] = a1.z;  As[kq8 + 7][r] = a1.w;
    };

    // ---- prologue: stage tile 0 -------------------------------------------
    {
        __builtin_amdgcn_global_load_lds(
            (const __attribute__((address_space(1))) unsigned int*)bsrc0,
            (__attribute__((address_space(3))) unsigned int*)&Bs[w * 4][0],
            16, 0, 0);
        float4 a0 = *(const float4*)(abase);
        float4 a1 = *(const float4*)(abase + 4);
        write_a(a0, a1);
    }
    __syncthreads();   // drains vmcnt+lgkm: tile 0 ready

    // ---- main loop: compute(t) | A-prefetch(t+1) -> bar -> stage -> bar ---
    for (int t = 0; t < 16; ++t) {
        float4 a0n, a1n;
        if (t < 15) {                       // issue A(t+1) early (reg dest)
            const float* ap = abase + (t + 1) * 16;
            a0n = *(const float4*)(ap);
            a1n = *(const float4*)(ap + 4);
        }

        #pragma unroll 4
        for (int k = 0; k < 16; ++k) {
            float4 a  = *(const float4*)&As[k][tr * 8];       // broadcast
            float4 a2 = *(const float4*)&As[k][tr * 8 + 4];   // broadcast
            float4 b  = *(const float4*)&Bs[k][tc * 4];       // 2-way free
            acc[0][0] = fmaf(a.x,  b.x, acc[0][0]); acc[0][1] = fmaf(a.x,  b.y, acc[0][1]);
            acc[0][2] = fmaf(a.x,  b.z, acc[0][2]); acc[0][3] = fmaf(a.x,  b.w, acc[0][3]);
            acc[1][0] = fmaf(a.y,  b.x, acc[1][0]); acc[1][1] = fmaf(a.y,  b.y, acc[1][1]);
            acc[1][2] = fmaf(a.y,  b.z, acc[1][2]); acc[1][3] = fmaf(a.y,  b.w, acc[1][3]);
            acc[2][0] = fmaf(a.z,  b.x, acc[2][0]); acc[2][1] = fmaf(a.z,  b.y, acc[2][1]);
            acc[2][2] = fmaf(a.z,  b.z, acc[2][2]); acc[2][3] = fmaf(a.z,  b.w, acc[2][3]);
            acc[3][0] = fmaf(a.w,  b.x, acc[3][0]); acc[3][1] = fmaf(a.w,  b.y, acc[3][1]);
            acc[3][2] = fmaf(a.w,  b.z, acc[3][2]); acc[3][3] = fmaf(a.w,  b.w, acc[3][3]);
            acc[4][0] = fmaf(a2.x, b.x, acc[4][0]); acc[4][1] = fmaf(a2.x, b.y, acc[4][1]);
            acc[4][2] = fmaf(a2.x, b.z, acc[4][2]); acc[4][3] = fmaf(a2.x, b.w, acc[4][3]);
            acc[5][0] = fmaf(a2.y, b.x, acc[5][0]); acc[5][1] = fmaf(a2.y, b.y, acc[5][1]);
            acc[5][2] = fmaf(a2.y, b.z, acc[5][2]); acc[5][3] = fmaf(a2.y, b.w, acc[5][3]);
            acc[6][0] = fmaf(a2.z, b.x, acc[6][0]); acc[6][1] = fmaf(a2.z, b.y, acc[6][1]);
            acc[6][2] = fmaf(a2.z, b.z, acc[6][2]); acc[6][3] = fmaf(a2.z, b.w, acc[6][3]);
            acc[7][0] = fmaf(a2.w, b.x, acc[7][0]); acc[7][1] = fmaf(a2.w, b.y, acc[7][1]);
            acc[7][2] = fmaf(a2.w, b.z, acc[7][2]); acc[7][3] = fmaf(a2.w, b.w, acc[7][3]);
        }

        __syncthreads();                    // all waves done reading tile t
        if (t < 15) {
            int k0 = (t + 1) * 16;
            __builtin_amdgcn_global_load_lds(
                (const __attribute__((address_space(1))) unsigned int*)(bsrc0 + (size_t)k0 * HDIM),
                (__attribute__((address_space(3))) unsigned int*)&Bs[w * 4][0],
                16, 0, 0);
            write_a(a0n, a1n);              // A data already in flight/arrived
            __syncthreads();                // drains vmcnt: tile t+1 ready
        }
    }

    // ---- epilogue: bias+relu, project to 2, 16-lane reduce, LDS pool ------
    float pc[8][2] = {};
    #pragma unroll
    for (int j = 0; j < 4; ++j) {
        int col = n0 + tc * 4 + j;
        float bcol = b2[col];
        float wc0 = Wc[col * 2 + 0], wc1 = Wc[col * 2 + 1];
        #pragma unroll
        for (int i = 0; i < 8; ++i) {
            float h = fmaxf(acc[i][j] + bcol, 0.0f);
            pc[i][0] = fmaf(h, wc0, pc[i][0]);
            pc[i][1] = fmaf(h, wc1, pc[i][1]);
        }
    }
    #pragma unroll
    for (int off = 8; off > 0; off >>= 1) {     // reduce the 16 tc lanes
        #pragma unroll
        for (int i = 0; i < 8; ++i) {
            pc[i][0] += __shfl_xor(pc[i][0], off);
            pc[i][1] += __shfl_xor(pc[i][1], off);
        }
    }
    if (tc == 0) {
        #pragma unroll
        for (int i = 0; i < 8; ++i) {
            int rr = m0 + tr * 8 + i;
            if (rr < N) {
                int g = gid[rr];
                atomicAdd(&Lpool[g * 2 + 0], pc[i][0]);
                atomicAdd(&Lpool[g * 2 + 1], pc[i][1]);
            }
        }
    }
    __syncthreads();
    float v = Lpool[tid];
    if (tid < 2 * G && v != 0.0f) atomicAdd(&pool[tid], v);
}

__global__ __launch_bounds__(256) void finalize_kernel(
    const float* __restrict__ pool, const int* __restrict__ gcnt,
    const float* __restrict__ bc, float* __restrict__ out, int G)
{
    int g = threadIdx.x;
    if (g < G) {
        float c = fmaxf((float)gcnt[g], 1.0f);
        out[2 * g + 0] = pool[2 * g + 0] / c + bc[0];
        out[2 * g + 1] = pool[2 * g + 1] / c + bc[1];
    }
}

extern "C" void kernel_launch(void* const* d_in, const int* in_sizes, int n_in,
                              void* d_out, int out_size, void* d_ws, size_t ws_size,
                              hipStream_t stream)
{
    const float* t  = (const float*)d_in[0];
    const float* u  = (const float*)d_in[1];
    const int* esrc = (const int*)d_in[2];
    const int* edst = (const int*)d_in[3];
    const int* gid  = (const int*)d_in[4];
    const float* W1 = (const float*)d_in[6];
    const float* b1 = (const float*)d_in[7];
    const float* W2 = (const float*)d_in[8];
    const float* b2 = (const float*)d_in[9];
    const float* Wc = (const float*)d_in[10];
    const float* bc = (const float*)d_in[11];
    float* out = (float*)d_out;

    int N = in_sizes[0];
    int E = in_sizes[2];
    int G = out_size / 2;

    char* ws = (char*)d_ws;
    size_t off = 0;
    auto take = [&](size_t bytes) {
        size_t o = off;
        off += (bytes + 15) & ~(size_t)15;
        return o;
    };
    int*    deg_out = (int*)   (ws + take(4 * (size_t)N));
    int*    deg_in  = (int*)   (ws + take(4 * (size_t)N));
    float*  pool    = (float*) (ws + take(8 * (size_t)G));
    int*    gcnt    = (int*)   (ws + take(4 * (size_t)G));
    size_t  zbytes  = off;                               // zero everything above
    float*  os      = (float*) (ws + take(4 * (size_t)N));
    float*  isc     = (float*) (ws + take(4 * (size_t)N));
    float2* pre     = (float2*)(ws + take(8 * (size_t)N));
    int*    offs    = (int*)   (ws + take(4 * (size_t)(N + 1)));
    int*    cursor  = (int*)   (ws + take(4 * (size_t)N));
    int*    loc     = (int*)   (ws + take(4 * (size_t)N));
    int*    partials= (int*)   (ws + take(4 * 64));
    int*    csr     = (int*)   (ws + take(4 * (size_t)E));
    float4* pack    = (float4*)(ws + take(16 * (size_t)N));
    float*  agg2    = (float*) (ws + take((size_t)N * HDIM * 4));

    hipMemsetAsync(ws, 0, zbytes, stream);

    int eb = (E + 255) / 256;
    int nb = (N + 255) / 256;
    int sb = (N + 1023) / 1024;     // scan blocks (<=64 for N<=65536)
    deg_kernel          <<<eb, 256, 0, stream>>>(esrc, edst, deg_out, deg_in, E);
    node_kernel         <<<nb, 256, 0, stream>>>(deg_out, deg_in, gid, t, u, os, isc, pre, gcnt, N);
    scan_local_kernel   <<<sb, 1024, 0, stream>>>(deg_in, loc, partials, N);
    scan_partials_kernel<<<1, 64, 0, stream>>>(partials, sb);
    scan_add_kernel     <<<nb, 256, 0, stream>>>(loc, partials, offs, cursor, N, E);
    fill_csr_kernel     <<<eb, 256, 0, stream>>>(esrc, edst, cursor, csr, E);
    vpack_kernel        <<<(N + 15) / 16, 256, 0, stream>>>(offs, csr, pre, os, isc, pack, N);
    agg_kernel          <<<(N + 3) / 4, 256, 0, stream>>>(offs, csr, pack, isc, W1, b1, agg2, N);
    gemm_pool_kernel    <<<((N + 127) / 128) * 4, 256, 0, stream>>>(agg2, W2, b2, Wc, gid, pool, N, G);
    finalize_kernel     <<<1, 256, 0, stream>>>(pool, gcnt, bc, out, G);
}

// Round 11
// 365.764 us; speedup vs baseline: 2.4995x; 1.3092x over previous
//
#include <hip/hip_runtime.h>

// ---------------------------------------------------------------------------
// GCN forward: h0=[time,type] -> GraphConv(relu) -> GraphConv(relu)
//              -> per-graph mean pool -> linear [G,2]
//
//  * degrees via int atomics; scales = 1/sqrt(max(deg,1))
//  * graph counts via SORTED-gid segment boundaries (NO atomics — round 9
//    showed atomicAdd(&gcnt[gid[i]]) on sorted gid = 120us same-address
//    serialization, the slowest dispatch in the whole pipeline)
//  * CSR-by-dst (histogram + 3-kernel device-wide scan + bucket fill)
//  * vpack: CSR layer-1 aggregate fused with pack build (no atomics)
//  * agg: WAVE per node; per edge RECOMPUTE h1[src]=relu(v_src@W1+b1) in regs
//  * gemm_pool: h2 = relu(agg2@W2+b2); p = h2@Wc; pool via LDS then global.
//    BM=128 BN=64 BK=16, 8x4/thread (~70 regs, 6+ waves/SIMD), grid 1564.
// ---------------------------------------------------------------------------

#define HDIM 256

__global__ __launch_bounds__(256) void deg_kernel(
    const int* __restrict__ src, const int* __restrict__ dst,
    int* __restrict__ deg_out, int* __restrict__ deg_in, int E)
{
    int e = blockIdx.x * 256 + threadIdx.x;
    if (e < E) {
        atomicAdd(&deg_out[src[e]], 1);
        atomicAdd(&deg_in[dst[e]], 1);
    }
}

// elementwise node prep + sorted-gid segment boundaries (no atomics)
__global__ __launch_bounds__(256) void node_kernel(
    const int* __restrict__ deg_out, const int* __restrict__ deg_in,
    const int* __restrict__ gid, const float* __restrict__ t,
    const float* __restrict__ u, float* __restrict__ os,
    float* __restrict__ isc, float2* __restrict__ pre,
    int* __restrict__ gfirst, int* __restrict__ glast, int N)
{
    int i = blockIdx.x * 256 + threadIdx.x;
    if (i < N) {
        float o = 1.0f / sqrtf(fmaxf((float)deg_out[i], 1.0f));
        os[i]  = o;
        isc[i] = 1.0f / sqrtf(fmaxf((float)deg_in[i], 1.0f));
        pre[i] = make_float2(o * t[i], o * u[i]);
        int g = gid[i];
        if (i == 0 || gid[i - 1] != g) gfirst[g] = i;       // unique writer
        if (i == N - 1 || gid[i + 1] != g) glast[g] = i + 1; // unique writer
    }
}

// ---- device-wide exclusive scan of deg_in (3 kernels, N <= 64*1024) --------
__global__ __launch_bounds__(1024) void scan_local_kernel(
    const int* __restrict__ deg, int* __restrict__ loc,
    int* __restrict__ partials, int N)
{
    __shared__ int lds[1024];
    int tid = threadIdx.x;
    int idx = blockIdx.x * 1024 + tid;
    int x = (idx < N) ? deg[idx] : 0;
    int val = x;
    lds[tid] = val;
    __syncthreads();
    for (int d = 1; d < 1024; d <<= 1) {
        int tv = (tid >= d) ? lds[tid - d] : 0;
        __syncthreads();
        val += tv;
        lds[tid] = val;
        __syncthreads();
    }
    if (idx < N) loc[idx] = val - x;              // exclusive within block
    if (tid == 1023) partials[blockIdx.x] = val;  // block total
}

__global__ __launch_bounds__(64) void scan_partials_kernel(
    int* __restrict__ partials, int nb)
{
    int lane = threadIdx.x;
    int x = (lane < nb) ? partials[lane] : 0;
    int v = x;
    #pragma unroll
    for (int d = 1; d < 64; d <<= 1) {
        int tv = __shfl_up(v, d);
        if (lane >= d) v += tv;
    }
    if (lane < nb) partials[lane] = v - x;        // exclusive
}

__global__ __launch_bounds__(256) void scan_add_kernel(
    const int* __restrict__ loc, const int* __restrict__ partials,
    int* __restrict__ offs, int* __restrict__ cursor, int N, int E)
{
    int i = blockIdx.x * 256 + threadIdx.x;
    if (i < N) {
        int vv = loc[i] + partials[i >> 10];
        offs[i] = vv;
        cursor[i] = vv;
    }
    if (i == 0) offs[N] = E;
}
// ---------------------------------------------------------------------------

__global__ __launch_bounds__(256) void fill_csr_kernel(
    const int* __restrict__ src, const int* __restrict__ dst,
    int* __restrict__ cursor, int* __restrict__ csr, int E)
{
    int e = blockIdx.x * 256 + threadIdx.x;
    if (e < E) {
        int pos = atomicAdd(&cursor[dst[e]], 1);
        csr[pos] = src[e];
    }
}

// layer-1 aggregate via CSR (no atomics) fused with pack build.
__global__ __launch_bounds__(256) void vpack_kernel(
    const int* __restrict__ offs, const int* __restrict__ csr,
    const float2* __restrict__ pre, const float* __restrict__ os,
    const float* __restrict__ isc, float4* __restrict__ pack, int N)
{
    int grp = threadIdx.x >> 4;
    int l   = threadIdx.x & 15;
    int i = blockIdx.x * 16 + grp;
    if (i >= N) return;
    int e0 = offs[i], e1 = offs[i + 1];
    float a0 = 0.0f, a1 = 0.0f;
    for (int e = e0 + l; e < e1; e += 16) {
        float2 pv = pre[csr[e]];
        a0 += pv.x;
        a1 += pv.y;
    }
    #pragma unroll
    for (int d = 8; d; d >>= 1) {
        a0 += __shfl_xor(a0, d);
        a1 += __shfl_xor(a1, d);
    }
    if (l == 0) {
        float s2 = isc[i];
        pack[i] = make_float4(a0 * s2, a1 * s2, os[i], 0.0f);
    }
}

// one WAVE per node; lane owns channels lane + 64q (q=0..3).
__global__ __launch_bounds__(256) void agg_kernel(
    const int* __restrict__ offs, const int* __restrict__ csr,
    const float4* __restrict__ pack, const float* __restrict__ isc,
    const float* __restrict__ W1, const float* __restrict__ b1,
    float* __restrict__ agg2, int N)
{
    int wave = threadIdx.x >> 6;
    int lane = threadIdx.x & 63;
    int i = blockIdx.x * 4 + wave;
    if (i >= N) return;

    float w0[4], w1[4], bb[4], acc[4] = {0.f, 0.f, 0.f, 0.f};
    #pragma unroll
    for (int q = 0; q < 4; ++q) {
        int j = lane + 64 * q;
        w0[q] = W1[j];
        w1[q] = W1[HDIM + j];
        bb[q] = b1[j];
    }

    int e0 = offs[i], e1 = offs[i + 1];
    for (int e = e0; e < e1; ++e) {
        int s = csr[e];
        float4 pk = pack[s];
        #pragma unroll
        for (int q = 0; q < 4; ++q) {
            float h = fmaxf(fmaf(pk.x, w0[q], fmaf(pk.y, w1[q], bb[q])), 0.0f);
            acc[q] = fmaf(pk.z, h, acc[q]);
        }
    }
    float s2 = isc[i];
    #pragma unroll
    for (int q = 0; q < 4; ++q)
        agg2[(size_t)i * HDIM + lane + 64 * q] = acc[q] * s2;
}

// fused GEMM + pool. BM=128 BN=64 BK=16; 256 thr; 8 rows x 4 cols per thread.
// tr=tid>>4 (16 row-groups of 8), tc=tid&15 (cols tc*4..+3).
// A k-major LDS [16][132] (pad: 16B-aligned rows, 2-way-free banks),
// B row-major [16][64] staged by global_load_lds (linear dest).
__global__ __launch_bounds__(256) void gemm_pool_kernel(
    const float* __restrict__ agg2, const float* __restrict__ W2,
    const float* __restrict__ b2, const float* __restrict__ Wc,
    const int* __restrict__ gid, float* __restrict__ pool, int N, int G)
{
    __shared__ float As[16][132];   // 8448 B
    __shared__ float Bs[16][64];    // 4096 B
    __shared__ float Lpool[256];    // per-block graph pool (G<=128)
    int tid  = threadIdx.x;
    int bm   = blockIdx.x >> 2;
    int bn   = blockIdx.x & 3;
    int m0   = bm * 128;
    int n0   = bn * 64;
    int tr   = tid >> 4;
    int tc   = tid & 15;
    int w    = tid >> 6;
    int lane = tid & 63;
    int r    = tid >> 1;            // A staging row 0..127
    int kq8  = (tid & 1) * 8;       // A staging k sub-offset (0 or 8)

    Lpool[tid] = 0.0f;

    float acc[8][4] = {};

    int arow = m0 + r;
    if (arow > N - 1) arow = N - 1;           // clamped rows discarded at epilogue
    const float* abase = agg2 + (size_t)arow * HDIM + kq8;
    // B source row/col for this lane (wave w stages rows w*4..w*4+3)
    const float* bsrc0 = W2 + (size_t)(w * 4 + (lane >> 4)) * HDIM + n0 + (lane & 15) * 4;

    auto write_a = [&](const float4& a0, const float4& a1) {
        As[kq8 + 0][r] = a0.x;  As[kq8 + 1][r] = a0.y;
        As[kq8 + 2][r] = a0.z;  As[kq8 + 3][r] = a0.w;
        As[kq8 + 4][r] = a1.x;  As[kq8 + 5][r] = a1.y;
        As[kq8 + 6][r] = a1.z;  As[kq8 + 7][r] = a1.w;
    };

    // ---- prologue: stage tile 0 -------------------------------------------
    {
        __builtin_amdgcn_global_load_lds(
            (const __attribute__((address_space(1))) unsigned int*)bsrc0,
            (__attribute__((address_space(3))) unsigned int*)&Bs[w * 4][0],
            16, 0, 0);
        float4 a0 = *(const float4*)(abase);
        float4 a1 = *(const float4*)(abase + 4);
        write_a(a0, a1);
    }
    __syncthreads();   // drains vmcnt+lgkm: tile 0 ready

    // ---- main loop: compute(t) | A-prefetch(t+1) -> bar -> stage -> bar ---
    for (int t = 0; t < 16; ++t) {
        float4 a0n, a1n;
        if (t < 15) {                       // issue A(t+1) early (reg dest)
            const float* ap = abase + (t + 1) * 16;
            a0n = *(const float4*)(ap);
            a1n = *(const float4*)(ap + 4);
        }

        #pragma unroll 4
        for (int k = 0; k < 16; ++k) {
            float4 a  = *(const float4*)&As[k][tr * 8];       // broadcast
            float4 a2 = *(const float4*)&As[k][tr * 8 + 4];   // broadcast
            float4 b  = *(const float4*)&Bs[k][tc * 4];       // 2-way free
            acc[0][0] = fmaf(a.x,  b.x, acc[0][0]); acc[0][1] = fmaf(a.x,  b.y, acc[0][1]);
            acc[0][2] = fmaf(a.x,  b.z, acc[0][2]); acc[0][3] = fmaf(a.x,  b.w, acc[0][3]);
            acc[1][0] = fmaf(a.y,  b.x, acc[1][0]); acc[1][1] = fmaf(a.y,  b.y, acc[1][1]);
            acc[1][2] = fmaf(a.y,  b.z, acc[1][2]); acc[1][3] = fmaf(a.y,  b.w, acc[1][3]);
            acc[2][0] = fmaf(a.z,  b.x, acc[2][0]); acc[2][1] = fmaf(a.z,  b.y, acc[2][1]);
            acc[2][2] = fmaf(a.z,  b.z, acc[2][2]); acc[2][3] = fmaf(a.z,  b.w, acc[2][3]);
            acc[3][0] = fmaf(a.w,  b.x, acc[3][0]); acc[3][1] = fmaf(a.w,  b.y, acc[3][1]);
            acc[3][2] = fmaf(a.w,  b.z, acc[3][2]); acc[3][3] = fmaf(a.w,  b.w, acc[3][3]);
            acc[4][0] = fmaf(a2.x, b.x, acc[4][0]); acc[4][1] = fmaf(a2.x, b.y, acc[4][1]);
            acc[4][2] = fmaf(a2.x, b.z, acc[4][2]); acc[4][3] = fmaf(a2.x, b.w, acc[4][3]);
            acc[5][0] = fmaf(a2.y, b.x, acc[5][0]); acc[5][1] = fmaf(a2.y, b.y, acc[5][1]);
            acc[5][2] = fmaf(a2.y, b.z, acc[5][2]); acc[5][3] = fmaf(a2.y, b.w, acc[5][3]);
            acc[6][0] = fmaf(a2.z, b.x, acc[6][0]); acc[6][1] = fmaf(a2.z, b.y, acc[6][1]);
            acc[6][2] = fmaf(a2.z, b.z, acc[6][2]); acc[6][3] = fmaf(a2.z, b.w, acc[6][3]);
            acc[7][0] = fmaf(a2.w, b.x, acc[7][0]); acc[7][1] = fmaf(a2.w, b.y, acc[7][1]);
            acc[7][2] = fmaf(a2.w, b.z, acc[7][2]); acc[7][3] = fmaf(a2.w, b.w, acc[7][3]);
        }

        __syncthreads();                    // all waves done reading tile t
        if (t < 15) {
            int k0 = (t + 1) * 16;
            __builtin_amdgcn_global_load_lds(
                (const __attribute__((address_space(1))) unsigned int*)(bsrc0 + (size_t)k0 * HDIM),
                (__attribute__((address_space(3))) unsigned int*)&Bs[w * 4][0],
                16, 0, 0);
            write_a(a0n, a1n);              // A data already in flight/arrived
            __syncthreads();                // drains vmcnt: tile t+1 ready
        }
    }

    // ---- epilogue: bias+relu, project to 2, 16-lane reduce, LDS pool ------
    float pc[8][2] = {};
    #pragma unroll
    for (int j = 0; j < 4; ++j) {
        int col = n0 + tc * 4 + j;
        float bcol = b2[col];
        float wc0 = Wc[col * 2 + 0], wc1 = Wc[col * 2 + 1];
        #pragma unroll
        for (int i = 0; i < 8; ++i) {
            float h = fmaxf(acc[i][j] + bcol, 0.0f);
            pc[i][0] = fmaf(h, wc0, pc[i][0]);
            pc[i][1] = fmaf(h, wc1, pc[i][1]);
        }
    }
    #pragma unroll
    for (int off = 8; off > 0; off >>= 1) {     // reduce the 16 tc lanes
        #pragma unroll
        for (int i = 0; i < 8; ++i) {
            pc[i][0] += __shfl_xor(pc[i][0], off);
            pc[i][1] += __shfl_xor(pc[i][1], off);
        }
    }
    if (tc == 0) {
        #pragma unroll
        for (int i = 0; i < 8; ++i) {
            int rr = m0 + tr * 8 + i;
            if (rr < N) {
                int g = gid[rr];
                atomicAdd(&Lpool[g * 2 + 0], pc[i][0]);
                atomicAdd(&Lpool[g * 2 + 1], pc[i][1]);
            }
        }
    }
    __syncthreads();
    float v = Lpool[tid];
    if (tid < 2 * G && v != 0.0f) atomicAdd(&pool[tid], v);
}

__global__ __launch_bounds__(256) void finalize_kernel(
    const float* __restrict__ pool, const int* __restrict__ gfirst,
    const int* __restrict__ glast, const float* __restrict__ bc,
    float* __restrict__ out, int G)
{
    int g = threadIdx.x;
    if (g < G) {
        float c = fmaxf((float)(glast[g] - gfirst[g]), 1.0f);
        out[2 * g + 0] = pool[2 * g + 0] / c + bc[0];
        out[2 * g + 1] = pool[2 * g + 1] / c + bc[1];
    }
}

extern "C" void kernel_launch(void* const* d_in, const int* in_sizes, int n_in,
                              void* d_out, int out_size, void* d_ws, size_t ws_size,
                              hipStream_t stream)
{
    const float* t  = (const float*)d_in[0];
    const float* u  = (const float*)d_in[1];
    const int* esrc = (const int*)d_in[2];
    const int* edst = (const int*)d_in[3];
    const int* gid  = (const int*)d_in[4];
    const float* W1 = (const float*)d_in[6];
    const float* b1 = (const float*)d_in[7];
    const float* W2 = (const float*)d_in[8];
    const float* b2 = (const float*)d_in[9];
    const float* Wc = (const float*)d_in[10];
    const float* bc = (const float*)d_in[11];
    float* out = (float*)d_out;

    int N = in_sizes[0];
    int E = in_sizes[2];
    int G = out_size / 2;

    char* ws = (char*)d_ws;
    size_t off = 0;
    auto take = [&](size_t bytes) {
        size_t o = off;
        off += (bytes + 15) & ~(size_t)15;
        return o;
    };
    int*    deg_out = (int*)   (ws + take(4 * (size_t)N));
    int*    deg_in  = (int*)   (ws + take(4 * (size_t)N));
    float*  pool    = (float*) (ws + take(8 * (size_t)G));
    int*    gfirst  = (int*)   (ws + take(4 * (size_t)G));
    int*    glast   = (int*)   (ws + take(4 * (size_t)G));
    size_t  zbytes  = off;                               // zero everything above
    float*  os      = (float*) (ws + take(4 * (size_t)N));
    float*  isc     = (float*) (ws + take(4 * (size_t)N));
    float2* pre     = (float2*)(ws + take(8 * (size_t)N));
    int*    offs    = (int*)   (ws + take(4 * (size_t)(N + 1)));
    int*    cursor  = (int*)   (ws + take(4 * (size_t)N));
    int*    loc     = (int*)   (ws + take(4 * (size_t)N));
    int*    partials= (int*)   (ws + take(4 * 64));
    int*    csr     = (int*)   (ws + take(4 * (size_t)E));
    float4* pack    = (float4*)(ws + take(16 * (size_t)N));
    float*  agg2    = (float*) (ws + take((size_t)N * HDIM * 4));

    hipMemsetAsync(ws, 0, zbytes, stream);

    int eb = (E + 255) / 256;
    int nb = (N + 255) / 256;
    int sb = (N + 1023) / 1024;     // scan blocks (<=64 for N<=65536)
    deg_kernel          <<<eb, 256, 0, stream>>>(esrc, edst, deg_out, deg_in, E);
    node_kernel         <<<nb, 256, 0, stream>>>(deg_out, deg_in, gid, t, u, os, isc, pre, gfirst, glast, N);
    scan_local_kernel   <<<sb, 1024, 0, stream>>>(deg_in, loc, partials, N);
    scan_partials_kernel<<<1, 64, 0, stream>>>(partials, sb);
    scan_add_kernel     <<<nb, 256, 0, stream>>>(loc, partials, offs, cursor, N, E);
    fill_csr_kernel     <<<eb, 256, 0, stream>>>(esrc, edst, cursor, csr, E);
    vpack_kernel        <<<(N + 15) / 16, 256, 0, stream>>>(offs, csr, pre, os, isc, pack, N);
    agg_kernel          <<<(N + 3) / 4, 256, 0, stream>>>(offs, csr, pack, isc, W1, b1, agg2, N);
    gemm_pool_kernel    <<<((N + 127) / 128) * 4, 256, 0, stream>>>(agg2, W2, b2, Wc, gid, pool, N, G);
    finalize_kernel     <<<1, 256, 0, stream>>>(pool, gfirst, glast, bc, out, G);
}